// Round 6
// baseline (96.606 us; speedup 1.0000x reference)
//
#include <hip/hip_runtime.h>

#define DEV static __device__ __forceinline__

// ================= lane-exchange primitives =================
// DPP ctrl: 0xB1 quad_perm[1,0,3,2] (xor1) | 0x4E quad_perm[2,3,0,1] (xor2)
//           0x1B quad_perm[3,2,1,0] (xor3) | 0x128 row_ror:8 (xor8)
//           0x141 row_half_mirror (xor7)
template <int CTRL>
DEV float dpp_mov(float v) {
    int i = __float_as_int(v);
    i = __builtin_amdgcn_update_dpp(i, i, CTRL, 0xF, 0xF, false);
    return __int_as_float(i);
}
template <int PAT>
DEV float swz(float v) {
    return __int_as_float(__builtin_amdgcn_ds_swizzle(__float_as_int(v), PAT));
}
DEV float bperm(int byteaddr, float v) {
    return __int_as_float(__builtin_amdgcn_ds_bpermute(byteaddr, __float_as_int(v)));
}

#if __has_builtin(__builtin_amdgcn_permlane16_swap)
#define HAVE_PL16 1
DEV void pl16_pair(float v, float &r0, float &r1) {
    auto r = __builtin_amdgcn_permlane16_swap(__float_as_int(v), __float_as_int(v),
                                              false, false);
    r0 = __int_as_float((int)r[0]);
    r1 = __int_as_float((int)r[1]);
}
#endif
#if __has_builtin(__builtin_amdgcn_permlane32_swap)
#define HAVE_PL32 1
DEV void pl32_pair(float v, float &r0, float &r1) {
    auto r = __builtin_amdgcn_permlane32_swap(__float_as_int(v), __float_as_int(v),
                                              false, false);
    r0 = __int_as_float((int)r[0]);
    r1 = __int_as_float((int)r[1]);
}
#endif

// Full-wave sum; r0+r1 after a swap is own+partner regardless of direction.
DEV float wave_sum(float v, int a32) {
    v += dpp_mov<0xB1>(v);
    v += dpp_mov<0x4E>(v);
    v += dpp_mov<0x141>(v);
    v += dpp_mov<0x128>(v);
#ifdef HAVE_PL16
    {
        float r0, r1;
        pl16_pair(v, r0, r1);
        v = r0 + r1;
    }
#else
    v += swz<0x401F>(v);
#endif
#ifdef HAVE_PL32
    {
        float r0, r1;
        pl32_pair(v, r0, r1);
        v = r0 + r1;
    }
#else
    v += bperm(a32, v);
#endif
    return v;
}

// Qubit q <-> bit P = 9-q of state index s = lane*16 + r.
// Lane bits 5..0 = state bits 9..4; reg bits 3..0 = state bits 3..0.
template <int P>
DEV void apply_ry(float (&re)[16], float (&im)[16], float c, float s, int lane,
                  int a32, bool cv16, bool cv32) {
    if constexpr (P == 9) {
#ifdef HAVE_PL32
        const bool hi = (lane & 32) != 0;
        const float fl = hi ? s : c;
        const float fh = hi ? c : -s;
        const float g0 = cv32 ? fl : fh;
        const float g1 = cv32 ? fh : fl;
#pragma unroll
        for (int r = 0; r < 16; ++r) {
            float x0, x1, y0, y1;
            pl32_pair(re[r], x0, x1);
            pl32_pair(im[r], y0, y1);
            re[r] = fmaf(g0, x0, g1 * x1);
            im[r] = fmaf(g0, y0, g1 * y1);
        }
#else
        const float sg = (lane & 32) ? s : -s;
#pragma unroll
        for (int r = 0; r < 16; ++r) {
            float pr = bperm(a32, re[r]);
            float pi = bperm(a32, im[r]);
            re[r] = fmaf(c, re[r], sg * pr);
            im[r] = fmaf(c, im[r], sg * pi);
        }
#endif
    } else if constexpr (P == 8) {
#ifdef HAVE_PL16
        const bool hi = (lane & 16) != 0;
        const float fl = hi ? s : c;
        const float fh = hi ? c : -s;
        const float g0 = cv16 ? fl : fh;
        const float g1 = cv16 ? fh : fl;
#pragma unroll
        for (int r = 0; r < 16; ++r) {
            float x0, x1, y0, y1;
            pl16_pair(re[r], x0, x1);
            pl16_pair(im[r], y0, y1);
            re[r] = fmaf(g0, x0, g1 * x1);
            im[r] = fmaf(g0, y0, g1 * y1);
        }
#else
        const float sg = (lane & 16) ? s : -s;
#pragma unroll
        for (int r = 0; r < 16; ++r) {
            float pr = swz<0x401F>(re[r]);
            float pi = swz<0x401F>(im[r]);
            re[r] = fmaf(c, re[r], sg * pr);
            im[r] = fmaf(c, im[r], sg * pi);
        }
#endif
    } else if constexpr (P >= 4) {
        constexpr int mask = 1 << (P - 4);
        const float sg = (lane & mask) ? s : -s;
#pragma unroll
        for (int r = 0; r < 16; ++r) {
            float pr, pi;
            if constexpr (mask == 8) {
                pr = dpp_mov<0x128>(re[r]);
                pi = dpp_mov<0x128>(im[r]);
            } else if constexpr (mask == 4) {
                // xor4 = xor7 o xor3, both DPP (round-2 proven)
                pr = dpp_mov<0x1B>(dpp_mov<0x141>(re[r]));
                pi = dpp_mov<0x1B>(dpp_mov<0x141>(im[r]));
            } else if constexpr (mask == 2) {
                pr = dpp_mov<0x4E>(re[r]);
                pi = dpp_mov<0x4E>(im[r]);
            } else {
                pr = dpp_mov<0xB1>(re[r]);
                pi = dpp_mov<0xB1>(im[r]);
            }
            re[r] = fmaf(c, re[r], sg * pr);
            im[r] = fmaf(c, im[r], sg * pi);
        }
    } else {
        constexpr int tb = 1 << P;
#pragma unroll
        for (int r = 0; r < 16; ++r) {
            if (!(r & tb)) {
                const int r2 = r | tb;
                float a0r = re[r], a1r = re[r2];
                float a0i = im[r], a1i = im[r2];
                re[r]  = fmaf(c, a0r, -s * a1r);
                re[r2] = fmaf(s, a0r,  c * a1r);
                im[r]  = fmaf(c, a0i, -s * a1i);
                im[r2] = fmaf(s, a0i,  c * a1i);
            }
        }
    }
}

// Composed lane map of CNOT chain C(q0->q1)..C(q4->q5).
DEV int g_of(int a) {
    a ^= ((a >> 1) & 1) ? 1 : 0;
    a ^= ((a >> 2) & 1) ? 2 : 0;
    a ^= ((a >> 3) & 1) ? 4 : 0;
    a ^= ((a >> 4) & 1) ? 8 : 0;
    a ^= ((a >> 5) & 1) ? 16 : 0;
    return a;
}

// RZ phase tables for one layer (p67 has the q0..q5 lane phase folded in).
DEV void build_rz_tables(const float (&zc)[10], const float (&zs)[10], int lane,
                         float (&p67r)[4], float (&p67i)[4], float (&p89r)[4],
                         float (&p89i)[4]) {
    float plr, pli;
    pli = ((lane >> 5) & 1) ? zs[0] : -zs[0];
    plr = zc[0];
#pragma unroll
    for (int q = 1; q < 6; ++q) {
        float sq = ((lane >> (5 - q)) & 1) ? zs[q] : -zs[q];
        float nr = plr * zc[q] - pli * sq;
        float ni = plr * sq + pli * zc[q];
        plr = nr; pli = ni;
    }
    const float c6 = zc[6], s6 = zs[6], c7 = zc[7], s7 = zs[7];
    const float c8 = zc[8], s8 = zs[8], c9 = zc[9], s9 = zs[9];
#pragma unroll
    for (int j = 0; j < 4; ++j) {
        float sg6 = (j >> 1) ? s6 : -s6;  // qubit6 <-> reg bit 3
        float sg7 = (j & 1) ? s7 : -s7;   // qubit7 <-> reg bit 2
        float ar = c6 * c7 - sg6 * sg7;
        float ai = c6 * sg7 + sg6 * c7;
        p67r[j] = ar * plr - ai * pli;
        p67i[j] = ar * pli + ai * plr;
        float sg8 = (j >> 1) ? s8 : -s8;  // qubit8 <-> reg bit 1
        float sg9 = (j & 1) ? s9 : -s9;   // qubit9 <-> reg bit 0
        p89r[j] = c8 * c9 - sg8 * sg9;
        p89i[j] = c8 * sg9 + sg8 * c9;
    }
}

// CNOT ring for BOTH elements: all 64 bpermutes issued in one batch.
DEV void cnot_ring2(float (&reA)[16], float (&imA)[16], float (&reB)[16],
                    float (&imB)[16], int cA_, int cB_, int lane) {
#pragma unroll
    for (int r = 0; r < 16; ++r) {
        const int addr = ((0x6996 >> r) & 1) ? cB_ : cA_;  // parity of r&15
        reA[r] = bperm(addr, reA[r]);
        imA[r] = bperm(addr, imA[r]);
        reB[r] = bperm(addr, reB[r]);
        imB[r] = bperm(addr, imB[r]);
    }
    {
        const bool ctrl = (lane & 1) != 0;  // C(q5->q6)
#pragma unroll
        for (int r = 0; r < 8; ++r) {
            const int r2 = r | 8;
            float t0 = reA[r], t1 = reA[r2];
            reA[r]  = ctrl ? t1 : t0;
            reA[r2] = ctrl ? t0 : t1;
            float u0 = imA[r], u1 = imA[r2];
            imA[r]  = ctrl ? u1 : u0;
            imA[r2] = ctrl ? u0 : u1;
            float v0 = reB[r], v1 = reB[r2];
            reB[r]  = ctrl ? v1 : v0;
            reB[r2] = ctrl ? v0 : v1;
            float w0 = imB[r], w1 = imB[r2];
            imB[r]  = ctrl ? w1 : w0;
            imB[r2] = ctrl ? w0 : w1;
        }
    }
    // register renames: C(q6->q7), C(q7->q8), C(q8->q9)
#pragma unroll
    for (int r = 0; r < 16; ++r)
        if ((r & 8) && !(r & 4)) {
            const int r2 = r | 4;
            float t;
            t = reA[r]; reA[r] = reA[r2]; reA[r2] = t;
            t = imA[r]; imA[r] = imA[r2]; imA[r2] = t;
            t = reB[r]; reB[r] = reB[r2]; reB[r2] = t;
            t = imB[r]; imB[r] = imB[r2]; imB[r2] = t;
        }
#pragma unroll
    for (int r = 0; r < 16; ++r)
        if ((r & 4) && !(r & 2)) {
            const int r2 = r | 2;
            float t;
            t = reA[r]; reA[r] = reA[r2]; reA[r2] = t;
            t = imA[r]; imA[r] = imA[r2]; imA[r2] = t;
            t = reB[r]; reB[r] = reB[r2]; reB[r2] = t;
            t = imB[r]; imB[r] = imB[r2]; imB[r2] = t;
        }
#pragma unroll
    for (int r = 0; r < 16; ++r)
        if ((r & 2) && !(r & 1)) {
            const int r2 = r | 1;
            float t;
            t = reA[r]; reA[r] = reA[r2]; reA[r2] = t;
            t = imA[r]; imA[r] = imA[r2]; imA[r2] = t;
            t = reB[r]; reB[r] = reB[r2]; reB[r2] = t;
            t = imB[r]; imB[r] = imB[r2]; imB[r2] = t;
        }
}

// Layer 0 folded into the initial state for one element:
// initial RY(th_q) + layer-0 RY compose additively; pre-CNOT layer-0 state
// is a product state; layer-0 RZ phases applied per-qubit analytically.
DEV void fold0(const float (&th)[10], const float* __restrict__ w_ry,
               const float2* shz, int lane, float (&re)[16], float (&im)[16]) {
    float f0r[10], f0i[10], f1r[10], f1i[10];
#pragma unroll
    for (int q = 0; q < 10; ++q) {
        float hh = 0.5f * (th[q] + w_ry[q]);  // w_ry row 0 (raw angle)
        float sh_, ch_;
        __sincosf(hh, &sh_, &ch_);
        float2 z = shz[q];                    // (cos, sin) of w_rz[0,q]/2
        f0r[q] = ch_ * z.x;  f0i[q] = -ch_ * z.y;   // e^{-i z}
        f1r[q] = sh_ * z.x;  f1i[q] =  sh_ * z.y;   // e^{+i z}
    }
    float Lr, Li;
    {
        int bq = (lane >> 5) & 1;
        Lr = bq ? f1r[0] : f0r[0];
        Li = bq ? f1i[0] : f0i[0];
#pragma unroll
        for (int q = 1; q < 6; ++q) {
            int bb = (lane >> (5 - q)) & 1;
            float br = bb ? f1r[q] : f0r[q];
            float bi = bb ? f1i[q] : f0i[q];
            float nr = Lr * br - Li * bi;
            float ni = Lr * bi + Li * br;
            Lr = nr; Li = ni;
        }
    }
    float t67r[4], t67i[4], t89r[4], t89i[4];
#pragma unroll
    for (int j = 0; j < 4; ++j) {
        float ar = (j >> 1) ? f1r[6] : f0r[6];  // qubit6 <-> reg bit 3
        float ai = (j >> 1) ? f1i[6] : f0i[6];
        float br = (j & 1) ? f1r[7] : f0r[7];   // qubit7 <-> reg bit 2
        float bi = (j & 1) ? f1i[7] : f0i[7];
        float pr = ar * br - ai * bi;
        float pi = ar * bi + ai * br;
        t67r[j] = pr * Lr - pi * Li;            // lane factor folded in
        t67i[j] = pr * Li + pi * Lr;
        float cr_ = (j >> 1) ? f1r[8] : f0r[8]; // qubit8 <-> reg bit 1
        float ci_ = (j >> 1) ? f1i[8] : f0i[8];
        float dr = (j & 1) ? f1r[9] : f0r[9];   // qubit9 <-> reg bit 0
        float di = (j & 1) ? f1i[9] : f0i[9];
        t89r[j] = cr_ * dr - ci_ * di;
        t89i[j] = cr_ * di + ci_ * dr;
    }
#pragma unroll
    for (int r = 0; r < 16; ++r) {
        const int j = r >> 2, k = r & 3;
        re[r] = t67r[j] * t89r[k] - t67i[j] * t89i[k];
        im[r] = t67r[j] * t89i[k] + t67i[j] * t89r[k];
    }
}

__global__ __launch_bounds__(256, 2) void dqc_main_kernel(
    const float* __restrict__ x, const float* __restrict__ pre_w,
    const float* __restrict__ pre_b, const float* __restrict__ post_w,
    const float* __restrict__ post_b, const float* __restrict__ w_ry,
    const float* __restrict__ w_rz, float* __restrict__ out, int B) {
    // Block-shared weight trig: [0..39] RY (row 0 unused), [40..79] RZ
    // (row 3 unused: last-layer RZ is a pure phase, cancels in |psi|^2).
    __shared__ float2 sh_trig[80];
    {
        int t = threadIdx.x;
        if (t < 80) {
            float ang = (t < 40 ? w_ry[t] : w_rz[t - 40]) * 0.5f;
            float sv, cv;
            __sincosf(ang, &sv, &cv);
            sh_trig[t] = make_float2(cv, sv);
        }
    }
    __syncthreads();

    const int lane = threadIdx.x & 63;
    const int wid = threadIdx.x >> 6;
    // Two batch elements per wave: weight-derived work shared, 2x ILP.
    const int b0 = (blockIdx.x * 4 + wid) * 2;
    const int b1 = b0 + 1;
    if (b0 >= B) return;

    const int a32 = (lane ^ 32) << 2;

    // Probe permlane*_swap direction (wave-uniform).
    bool cv16 = false, cv32 = false;
#ifdef HAVE_PL16
    {
        auto r = __builtin_amdgcn_permlane16_swap(lane, lane, false, false);
        cv16 = ((int)r[0] == (lane & ~16));
    }
#endif
#ifdef HAVE_PL32
    {
        auto r = __builtin_amdgcn_permlane32_swap(lane, lane, false, false);
        cv32 = ((int)r[0] == (lane & ~32));
    }
#endif

    const int h0 = lane ^ ((lane & 1) ? 32 : 0);
    const int cA = g_of(h0) << 2;
    const int cB = g_of(h0 ^ 32) << 2;

    // ---- q_in[b, i] = x[b] . pre_w[i] + pre_b[i]  (pre_w tile shared) ----
    float thA[10], thB[10];
#pragma unroll
    for (int i = 0; i < 10; ++i) { thA[i] = 0.f; thB[i] = 0.f; }
    const float4* xA4 = reinterpret_cast<const float4*>(x + (size_t)b0 * 512);
    const float4* xB4 = reinterpret_cast<const float4*>(x + (size_t)b1 * 512);
    const float4* pw4 = reinterpret_cast<const float4*>(pre_w);
    const bool haveB = (b1 < B);
#pragma unroll
    for (int k = 0; k < 2; ++k) {
        const int idx = lane + 64 * k;
        const float4 xa = xA4[idx];
        const float4 xb = haveB ? xB4[idx] : xa;
#pragma unroll
        for (int i = 0; i < 10; ++i) {
            const float4 wv = pw4[i * 128 + idx];
            thA[i] = fmaf(xa.x, wv.x, thA[i]);
            thA[i] = fmaf(xa.y, wv.y, thA[i]);
            thA[i] = fmaf(xa.z, wv.z, thA[i]);
            thA[i] = fmaf(xa.w, wv.w, thA[i]);
            thB[i] = fmaf(xb.x, wv.x, thB[i]);
            thB[i] = fmaf(xb.y, wv.y, thB[i]);
            thB[i] = fmaf(xb.z, wv.z, thB[i]);
            thB[i] = fmaf(xb.w, wv.w, thB[i]);
        }
    }
#pragma unroll
    for (int i = 0; i < 10; ++i) {
        thA[i] = wave_sum(thA[i], a32) + pre_b[i];
        thB[i] = wave_sum(thB[i], a32) + pre_b[i];
    }

    // ---- layer 0 folded into the initial product state, then ring ----
    float reA[16], imA[16], reB[16], imB[16];
    fold0(thA, w_ry, sh_trig + 40, lane, reA, imA);
    fold0(thB, w_ry, sh_trig + 40, lane, reB, imB);
    cnot_ring2(reA, imA, reB, imB, cA, cB, lane);

    // ---- layers 1..3; layer 3 skips RZ (phase) and ring (permutation) ----
#pragma unroll 1
    for (int l = 1; l < 4; ++l) {
        float yc[10], ys[10];
#pragma unroll
        for (int q = 0; q < 10; ++q) {
            float2 v = sh_trig[l * 10 + q];
            yc[q] = v.x; ys[q] = v.y;
        }
        apply_ry<9>(reA, imA, yc[0], ys[0], lane, a32, cv16, cv32);
        apply_ry<9>(reB, imB, yc[0], ys[0], lane, a32, cv16, cv32);
        apply_ry<8>(reA, imA, yc[1], ys[1], lane, a32, cv16, cv32);
        apply_ry<8>(reB, imB, yc[1], ys[1], lane, a32, cv16, cv32);
        apply_ry<7>(reA, imA, yc[2], ys[2], lane, a32, cv16, cv32);
        apply_ry<7>(reB, imB, yc[2], ys[2], lane, a32, cv16, cv32);
        apply_ry<6>(reA, imA, yc[3], ys[3], lane, a32, cv16, cv32);
        apply_ry<6>(reB, imB, yc[3], ys[3], lane, a32, cv16, cv32);
        apply_ry<5>(reA, imA, yc[4], ys[4], lane, a32, cv16, cv32);
        apply_ry<5>(reB, imB, yc[4], ys[4], lane, a32, cv16, cv32);
        apply_ry<4>(reA, imA, yc[5], ys[5], lane, a32, cv16, cv32);
        apply_ry<4>(reB, imB, yc[5], ys[5], lane, a32, cv16, cv32);
        apply_ry<3>(reA, imA, yc[6], ys[6], lane, a32, cv16, cv32);
        apply_ry<3>(reB, imB, yc[6], ys[6], lane, a32, cv16, cv32);
        apply_ry<2>(reA, imA, yc[7], ys[7], lane, a32, cv16, cv32);
        apply_ry<2>(reB, imB, yc[7], ys[7], lane, a32, cv16, cv32);
        apply_ry<1>(reA, imA, yc[8], ys[8], lane, a32, cv16, cv32);
        apply_ry<1>(reB, imB, yc[8], ys[8], lane, a32, cv16, cv32);
        apply_ry<0>(reA, imA, yc[9], ys[9], lane, a32, cv16, cv32);
        apply_ry<0>(reB, imB, yc[9], ys[9], lane, a32, cv16, cv32);

        if (l < 3) {
            float zc[10], zs[10];
#pragma unroll
            for (int q = 0; q < 10; ++q) {
                float2 w = sh_trig[40 + l * 10 + q];
                zc[q] = w.x; zs[q] = w.y;
            }
            float p67r[4], p67i[4], p89r[4], p89i[4];
            build_rz_tables(zc, zs, lane, p67r, p67i, p89r, p89i);
#pragma unroll
            for (int r = 0; r < 16; ++r) {
                const int j = r >> 2, k = r & 3;
                float t_r = reA[r] * p67r[j] - imA[r] * p67i[j];
                float t_i = reA[r] * p67i[j] + imA[r] * p67r[j];
                reA[r] = t_r * p89r[k] - t_i * p89i[k];
                imA[r] = t_r * p89i[k] + t_i * p89r[k];
                float u_r = reB[r] * p67r[j] - imB[r] * p67i[j];
                float u_i = reB[r] * p67i[j] + imB[r] * p67r[j];
                reB[r] = u_r * p89r[k] - u_i * p89i[k];
                imB[r] = u_r * p89i[k] + u_i * p89r[k];
            }
            cnot_ring2(reA, imA, reB, imB, cA, cB, lane);
        }
    }

    // ---- epilogue with the last CNOT ring folded into the coefficients.
    // Ring is GF(2)-linear: bit_j' = xor_{k<=j} bit_k (j>=1),
    // bit_0' = xor_{k=1..9} bit_k. So z'_j = prod_{k<=j} z_k,
    // z'_0 = z0*L5*R9 (z0^2=1). C'(t) = A_lane + L5*WR(r) +- t0.
    float A_lane = 0.f;
    float L = ((lane >> 5) & 1) ? -1.f : 1.f;  // z0 (qubit0 <-> lane bit5)
#pragma unroll
    for (int j = 1; j <= 5; ++j) {
        L = ((lane >> (5 - j)) & 1) ? -L : L;  // L = prefix product L_j
        A_lane += post_w[j] * L;
    }
    const float t0 = post_w[0] * (((lane >> 5) & 1) ? -L : L);  // w0*z0*L5
    const float Ap = A_lane + t0, Am = A_lane - t0;
    const float w6 = post_w[6], w7 = post_w[7], w8 = post_w[8], w9 = post_w[9];
    float accA = 0.f, accB = 0.f;
#pragma unroll
    for (int r = 0; r < 16; ++r) {
        // WR(r) = z6*(w6 + z7*(w7 + z8*(w8 + z9*w9))), signs compile-time
        float u = (r & 1) ? w8 - w9 : w8 + w9;       // w8 + z9*w9
        float v = (r & 2) ? w7 - u : w7 + u;         // w7 + z8*(...)
        float wv = (r & 4) ? w6 - v : w6 + v;        // w6 + z7*(...)
        float WR = (r & 8) ? -wv : wv;               // z6*(...)
        const float base = ((0x6996 >> r) & 1) ? Am : Ap;  // +- t0 via R9
        float coef = fmaf(L, WR, base);
        float pA = fmaf(reA[r], reA[r], imA[r] * imA[r]);
        accA = fmaf(pA, coef, accA);
        float pB = fmaf(reB[r], reB[r], imB[r] * imB[r]);
        accB = fmaf(pB, coef, accB);
    }
    accA = wave_sum(accA, a32);
    accB = wave_sum(accB, a32);
    if (lane == 0) {
        out[b0] = accA + post_b[0];
        if (haveB) out[b1] = accB + post_b[0];
    }
}

extern "C" void kernel_launch(void* const* d_in, const int* in_sizes, int n_in,
                              void* d_out, int out_size, void* d_ws, size_t ws_size,
                              hipStream_t stream) {
    const float* x      = (const float*)d_in[0];
    const float* pre_w  = (const float*)d_in[1];
    const float* pre_b  = (const float*)d_in[2];
    const float* post_w = (const float*)d_in[3];
    const float* post_b = (const float*)d_in[4];
    const float* w_ry   = (const float*)d_in[5];
    const float* w_rz   = (const float*)d_in[6];
    float* out = (float*)d_out;
    (void)d_ws; (void)ws_size;

    const int B = in_sizes[0] / 512;  // 4096
    const int waves = (B + 1) / 2;    // 2 elements per wave
    dqc_main_kernel<<<(waves + 3) / 4, 256, 0, stream>>>(
        x, pre_w, pre_b, post_w, post_b, w_ry, w_rz, out, B);
}

// Round 7
// 95.192 us; speedup vs baseline: 1.0149x; 1.0149x over previous
//
#include <hip/hip_runtime.h>

#define DEV static __device__ __forceinline__

// Packed pair type: component x = batch element A, component y = element B.
// On gfx950 (<2 x float>) fma/mul/add lower to v_pk_fma_f32 / v_pk_mul_f32 /
// v_pk_add_f32 (FeaturePackedFP32Ops) - one issue slot for both elements.
typedef float f2 __attribute__((ext_vector_type(2)));

DEV f2 pkfma(f2 a, f2 b, f2 c) { return __builtin_elementwise_fma(a, b, c); }
DEV f2 bc(float v) { return (f2){v, v}; }

// ================= lane-exchange primitives (b32, per half) =============
// DPP ctrl: 0xB1 quad_perm[1,0,3,2] (xor1) | 0x4E quad_perm[2,3,0,1] (xor2)
//           0x1B quad_perm[3,2,1,0] (xor3) | 0x128 row_ror:8 (xor8)
//           0x141 row_half_mirror (xor7)
template <int CTRL>
DEV float dpp_mov(float v) {
    int i = __float_as_int(v);
    i = __builtin_amdgcn_update_dpp(i, i, CTRL, 0xF, 0xF, false);
    return __int_as_float(i);
}
template <int PAT>
DEV float swz(float v) {
    return __int_as_float(__builtin_amdgcn_ds_swizzle(__float_as_int(v), PAT));
}
DEV float bperm(int byteaddr, float v) {
    return __int_as_float(__builtin_amdgcn_ds_bpermute(byteaddr, __float_as_int(v)));
}

template <int CTRL>
DEV f2 dpp2(f2 v) { return (f2){dpp_mov<CTRL>(v.x), dpp_mov<CTRL>(v.y)}; }
template <int PAT>
DEV f2 swz2(f2 v) { return (f2){swz<PAT>(v.x), swz<PAT>(v.y)}; }
DEV f2 bperm2(int addr, f2 v) {
    return (f2){bperm(addr, v.x), bperm(addr, v.y)};
}

#if __has_builtin(__builtin_amdgcn_permlane16_swap)
#define HAVE_PL16 1
DEV void pl16_pair(float v, float &r0, float &r1) {
    auto r = __builtin_amdgcn_permlane16_swap(__float_as_int(v), __float_as_int(v),
                                              false, false);
    r0 = __int_as_float((int)r[0]);
    r1 = __int_as_float((int)r[1]);
}
DEV void pl16_pair2(f2 v, f2 &r0, f2 &r1) {
    float a0, a1, b0, b1;
    pl16_pair(v.x, a0, a1);
    pl16_pair(v.y, b0, b1);
    r0 = (f2){a0, b0};
    r1 = (f2){a1, b1};
}
#endif
#if __has_builtin(__builtin_amdgcn_permlane32_swap)
#define HAVE_PL32 1
DEV void pl32_pair(float v, float &r0, float &r1) {
    auto r = __builtin_amdgcn_permlane32_swap(__float_as_int(v), __float_as_int(v),
                                              false, false);
    r0 = __int_as_float((int)r[0]);
    r1 = __int_as_float((int)r[1]);
}
DEV void pl32_pair2(f2 v, f2 &r0, f2 &r1) {
    float a0, a1, b0, b1;
    pl32_pair(v.x, a0, a1);
    pl32_pair(v.y, b0, b1);
    r0 = (f2){a0, b0};
    r1 = (f2){a1, b1};
}
#endif

// Packed full-wave sum (each half reduced independently).
DEV f2 wave_sum2(f2 v, int a32) {
    v += dpp2<0xB1>(v);
    v += dpp2<0x4E>(v);
    v += dpp2<0x141>(v);
    v += dpp2<0x128>(v);
#ifdef HAVE_PL16
    {
        f2 r0, r1;
        pl16_pair2(v, r0, r1);
        v = r0 + r1;
    }
#else
    v += swz2<0x401F>(v);
#endif
#ifdef HAVE_PL32
    {
        f2 r0, r1;
        pl32_pair2(v, r0, r1);
        v = r0 + r1;
    }
#else
    v += bperm2(a32, v);
#endif
    return v;
}

// Qubit q <-> bit P = 9-q of state index s = lane*16 + r.
// Lane bits 5..0 = state bits 9..4; reg bits 3..0 = state bits 3..0.
template <int P>
DEV void apply_ry2(f2 (&re)[16], f2 (&im)[16], float c, float s, int lane,
                   int a32, bool cv16, bool cv32) {
    if constexpr (P == 9) {
#ifdef HAVE_PL32
        const bool hi = (lane & 32) != 0;
        const float fl = hi ? s : c;
        const float fh = hi ? c : -s;
        const f2 g0 = bc(cv32 ? fl : fh);
        const f2 g1 = bc(cv32 ? fh : fl);
#pragma unroll
        for (int r = 0; r < 16; ++r) {
            f2 x0, x1, y0, y1;
            pl32_pair2(re[r], x0, x1);
            pl32_pair2(im[r], y0, y1);
            re[r] = pkfma(g0, x0, g1 * x1);
            im[r] = pkfma(g0, y0, g1 * y1);
        }
#else
        const f2 sg = bc((lane & 32) ? s : -s);
        const f2 cc = bc(c);
#pragma unroll
        for (int r = 0; r < 16; ++r) {
            f2 pr = bperm2(a32, re[r]);
            f2 pi = bperm2(a32, im[r]);
            re[r] = pkfma(cc, re[r], sg * pr);
            im[r] = pkfma(cc, im[r], sg * pi);
        }
#endif
    } else if constexpr (P == 8) {
#ifdef HAVE_PL16
        const bool hi = (lane & 16) != 0;
        const float fl = hi ? s : c;
        const float fh = hi ? c : -s;
        const f2 g0 = bc(cv16 ? fl : fh);
        const f2 g1 = bc(cv16 ? fh : fl);
#pragma unroll
        for (int r = 0; r < 16; ++r) {
            f2 x0, x1, y0, y1;
            pl16_pair2(re[r], x0, x1);
            pl16_pair2(im[r], y0, y1);
            re[r] = pkfma(g0, x0, g1 * x1);
            im[r] = pkfma(g0, y0, g1 * y1);
        }
#else
        const f2 sg = bc((lane & 16) ? s : -s);
        const f2 cc = bc(c);
#pragma unroll
        for (int r = 0; r < 16; ++r) {
            f2 pr = swz2<0x401F>(re[r]);
            f2 pi = swz2<0x401F>(im[r]);
            re[r] = pkfma(cc, re[r], sg * pr);
            im[r] = pkfma(cc, im[r], sg * pi);
        }
#endif
    } else if constexpr (P >= 4) {
        constexpr int mask = 1 << (P - 4);
        const f2 sg = bc((lane & mask) ? s : -s);
        const f2 cc = bc(c);
#pragma unroll
        for (int r = 0; r < 16; ++r) {
            f2 pr, pi;
            if constexpr (mask == 8) {
                pr = dpp2<0x128>(re[r]);
                pi = dpp2<0x128>(im[r]);
            } else if constexpr (mask == 4) {
                // xor4 = xor7 o xor3, both DPP (round-2 proven)
                pr = dpp2<0x1B>(dpp2<0x141>(re[r]));
                pi = dpp2<0x1B>(dpp2<0x141>(im[r]));
            } else if constexpr (mask == 2) {
                pr = dpp2<0x4E>(re[r]);
                pi = dpp2<0x4E>(im[r]);
            } else {
                pr = dpp2<0xB1>(re[r]);
                pi = dpp2<0xB1>(im[r]);
            }
            re[r] = pkfma(cc, re[r], sg * pr);
            im[r] = pkfma(cc, im[r], sg * pi);
        }
    } else {
        constexpr int tb = 1 << P;
        const f2 cc = bc(c);
        const f2 ss = bc(s);
        const f2 ms = bc(-s);
#pragma unroll
        for (int r = 0; r < 16; ++r) {
            if (!(r & tb)) {
                const int r2 = r | tb;
                f2 a0r = re[r], a1r = re[r2];
                f2 a0i = im[r], a1i = im[r2];
                re[r]  = pkfma(cc, a0r, ms * a1r);
                re[r2] = pkfma(ss, a0r, cc * a1r);
                im[r]  = pkfma(cc, a0i, ms * a1i);
                im[r2] = pkfma(ss, a0i, cc * a1i);
            }
        }
    }
}

// Composed lane map of CNOT chain C(q0->q1)..C(q4->q5).
DEV int g_of(int a) {
    a ^= ((a >> 1) & 1) ? 1 : 0;
    a ^= ((a >> 2) & 1) ? 2 : 0;
    a ^= ((a >> 3) & 1) ? 4 : 0;
    a ^= ((a >> 4) & 1) ? 8 : 0;
    a ^= ((a >> 5) & 1) ? 16 : 0;
    return a;
}

// RZ phase tables (scalar build, broadcast f2 output; p67 has the q0..q5
// lane phase folded in).
DEV void build_rz_tables_pk(const float (&zc)[10], const float (&zs)[10],
                            int lane, f2 (&p67r)[4], f2 (&p67i)[4],
                            f2 (&p89r)[4], f2 (&p89i)[4]) {
    float plr, pli;
    pli = ((lane >> 5) & 1) ? zs[0] : -zs[0];
    plr = zc[0];
#pragma unroll
    for (int q = 1; q < 6; ++q) {
        float sq = ((lane >> (5 - q)) & 1) ? zs[q] : -zs[q];
        float nr = plr * zc[q] - pli * sq;
        float ni = plr * sq + pli * zc[q];
        plr = nr; pli = ni;
    }
    const float c6 = zc[6], s6 = zs[6], c7 = zc[7], s7 = zs[7];
    const float c8 = zc[8], s8 = zs[8], c9 = zc[9], s9 = zs[9];
#pragma unroll
    for (int j = 0; j < 4; ++j) {
        float sg6 = (j >> 1) ? s6 : -s6;  // qubit6 <-> reg bit 3
        float sg7 = (j & 1) ? s7 : -s7;   // qubit7 <-> reg bit 2
        float ar = c6 * c7 - sg6 * sg7;
        float ai = c6 * sg7 + sg6 * c7;
        p67r[j] = bc(ar * plr - ai * pli);
        p67i[j] = bc(ar * pli + ai * plr);
        float sg8 = (j >> 1) ? s8 : -s8;  // qubit8 <-> reg bit 1
        float sg9 = (j & 1) ? s9 : -s9;   // qubit9 <-> reg bit 0
        p89r[j] = bc(c8 * c9 - sg8 * sg9);
        p89i[j] = bc(c8 * sg9 + sg8 * c9);
    }
}

// CNOT ring (physical), packed state.
DEV void cnot_ring_pk(f2 (&re)[16], f2 (&im)[16], int cA_, int cB_, int lane) {
#pragma unroll
    for (int r = 0; r < 16; ++r) {
        const int addr = ((0x6996 >> r) & 1) ? cB_ : cA_;  // parity of r&15
        re[r] = bperm2(addr, re[r]);
        im[r] = bperm2(addr, im[r]);
    }
    {
        const bool ctrl = (lane & 1) != 0;  // C(q5->q6)
#pragma unroll
        for (int r = 0; r < 8; ++r) {
            const int r2 = r | 8;
            f2 t0 = re[r], t1 = re[r2];
            re[r]  = ctrl ? t1 : t0;
            re[r2] = ctrl ? t0 : t1;
            f2 u0 = im[r], u1 = im[r2];
            im[r]  = ctrl ? u1 : u0;
            im[r2] = ctrl ? u0 : u1;
        }
    }
    // register renames: C(q6->q7), C(q7->q8), C(q8->q9)
#pragma unroll
    for (int r = 0; r < 16; ++r)
        if ((r & 8) && !(r & 4)) {
            const int r2 = r | 4;
            f2 t;
            t = re[r]; re[r] = re[r2]; re[r2] = t;
            t = im[r]; im[r] = im[r2]; im[r2] = t;
        }
#pragma unroll
    for (int r = 0; r < 16; ++r)
        if ((r & 4) && !(r & 2)) {
            const int r2 = r | 2;
            f2 t;
            t = re[r]; re[r] = re[r2]; re[r2] = t;
            t = im[r]; im[r] = im[r2]; im[r2] = t;
        }
#pragma unroll
    for (int r = 0; r < 16; ++r)
        if ((r & 2) && !(r & 1)) {
            const int r2 = r | 1;
            f2 t;
            t = re[r]; re[r] = re[r2]; re[r2] = t;
            t = im[r]; im[r] = im[r2]; im[r2] = t;
        }
}

// Layer 0 folded into the initial state (both elements packed):
// initial RY(th_q) + layer-0 RY compose additively; pre-CNOT layer-0 state
// is a product state; layer-0 RZ phases applied per-qubit analytically.
DEV void fold0_pk(const f2 (&th)[10], const float* __restrict__ w_ry,
                  const float2* shz, int lane, f2 (&re)[16], f2 (&im)[16]) {
    f2 f0r[10], f0i[10], f1r[10], f1i[10];
#pragma unroll
    for (int q = 0; q < 10; ++q) {
        f2 hh = (th[q] + bc(w_ry[q])) * bc(0.5f);  // w_ry row 0 (raw angle)
        float sA, cA, sB, cB;
        __sincosf(hh.x, &sA, &cA);
        __sincosf(hh.y, &sB, &cB);
        f2 ch = (f2){cA, cB}, sh = (f2){sA, sB};
        float2 z = shz[q];                         // (cos, sin) of w_rz[0,q]/2
        f0r[q] = ch * bc(z.x);  f0i[q] = ch * bc(-z.y);   // e^{-i z}
        f1r[q] = sh * bc(z.x);  f1i[q] = sh * bc(z.y);    // e^{+i z}
    }
    f2 Lr, Li;
    {
        int bq = (lane >> 5) & 1;
        Lr = bq ? f1r[0] : f0r[0];
        Li = bq ? f1i[0] : f0i[0];
#pragma unroll
        for (int q = 1; q < 6; ++q) {
            int bb = (lane >> (5 - q)) & 1;
            f2 br = bb ? f1r[q] : f0r[q];
            f2 bi = bb ? f1i[q] : f0i[q];
            f2 nr = pkfma(Li, -bi, Lr * br);
            f2 ni = pkfma(Li, br, Lr * bi);
            Lr = nr; Li = ni;
        }
    }
    f2 t67r[4], t67i[4], t89r[4], t89i[4];
#pragma unroll
    for (int j = 0; j < 4; ++j) {
        f2 ar = (j >> 1) ? f1r[6] : f0r[6];  // qubit6 <-> reg bit 3
        f2 ai = (j >> 1) ? f1i[6] : f0i[6];
        f2 br = (j & 1) ? f1r[7] : f0r[7];   // qubit7 <-> reg bit 2
        f2 bi = (j & 1) ? f1i[7] : f0i[7];
        f2 pr = pkfma(ai, -bi, ar * br);
        f2 pi = pkfma(ai, br, ar * bi);
        t67r[j] = pkfma(pi, -Li, pr * Lr);   // lane factor folded in
        t67i[j] = pkfma(pi, Lr, pr * Li);
        f2 cr_ = (j >> 1) ? f1r[8] : f0r[8]; // qubit8 <-> reg bit 1
        f2 ci_ = (j >> 1) ? f1i[8] : f0i[8];
        f2 dr = (j & 1) ? f1r[9] : f0r[9];   // qubit9 <-> reg bit 0
        f2 di = (j & 1) ? f1i[9] : f0i[9];
        t89r[j] = pkfma(ci_, -di, cr_ * dr);
        t89i[j] = pkfma(ci_, dr, cr_ * di);
    }
#pragma unroll
    for (int r = 0; r < 16; ++r) {
        const int j = r >> 2, k = r & 3;
        re[r] = pkfma(t67i[j], -t89i[k], t67r[j] * t89r[k]);
        im[r] = pkfma(t67i[j], t89r[k], t67r[j] * t89i[k]);
    }
}

__global__ __launch_bounds__(256, 2) void dqc_main_kernel(
    const float* __restrict__ x, const float* __restrict__ pre_w,
    const float* __restrict__ pre_b, const float* __restrict__ post_w,
    const float* __restrict__ post_b, const float* __restrict__ w_ry,
    const float* __restrict__ w_rz, float* __restrict__ out, int B) {
    // Block-shared weight trig: [0..39] RY (row 0 unused), [40..79] RZ
    // (row 3 unused: last-layer RZ is a pure phase, cancels in |psi|^2).
    __shared__ float2 sh_trig[80];
    {
        int t = threadIdx.x;
        if (t < 80) {
            float ang = (t < 40 ? w_ry[t] : w_rz[t - 40]) * 0.5f;
            float sv, cv;
            __sincosf(ang, &sv, &cv);
            sh_trig[t] = make_float2(cv, sv);
        }
    }
    __syncthreads();

    const int lane = threadIdx.x & 63;
    const int wid = threadIdx.x >> 6;
    // Two batch elements per wave, packed into <2 x float> lanes.
    const int b0 = (blockIdx.x * 4 + wid) * 2;
    const int b1 = b0 + 1;
    if (b0 >= B) return;

    const int a32 = (lane ^ 32) << 2;

    // Probe permlane*_swap direction (wave-uniform).
    bool cv16 = false, cv32 = false;
#ifdef HAVE_PL16
    {
        auto r = __builtin_amdgcn_permlane16_swap(lane, lane, false, false);
        cv16 = ((int)r[0] == (lane & ~16));
    }
#endif
#ifdef HAVE_PL32
    {
        auto r = __builtin_amdgcn_permlane32_swap(lane, lane, false, false);
        cv32 = ((int)r[0] == (lane & ~32));
    }
#endif

    const int h0 = lane ^ ((lane & 1) ? 32 : 0);
    const int cA = g_of(h0) << 2;
    const int cB = g_of(h0 ^ 32) << 2;

    // ---- q_in[b, i] = x[b] . pre_w[i] + pre_b[i]  (packed accumulators) ----
    f2 th[10];
#pragma unroll
    for (int i = 0; i < 10; ++i) th[i] = (f2){0.f, 0.f};
    const float4* xA4 = reinterpret_cast<const float4*>(x + (size_t)b0 * 512);
    const float4* xB4 = reinterpret_cast<const float4*>(x + (size_t)b1 * 512);
    const float4* pw4 = reinterpret_cast<const float4*>(pre_w);
    const bool haveB = (b1 < B);
#pragma unroll
    for (int k = 0; k < 2; ++k) {
        const int idx = lane + 64 * k;
        const float4 xa = xA4[idx];
        const float4 xb = haveB ? xB4[idx] : xa;
        const f2 xp0 = (f2){xa.x, xb.x};
        const f2 xp1 = (f2){xa.y, xb.y};
        const f2 xp2 = (f2){xa.z, xb.z};
        const f2 xp3 = (f2){xa.w, xb.w};
#pragma unroll
        for (int i = 0; i < 10; ++i) {
            const float4 wv = pw4[i * 128 + idx];
            th[i] = pkfma(xp0, bc(wv.x), th[i]);
            th[i] = pkfma(xp1, bc(wv.y), th[i]);
            th[i] = pkfma(xp2, bc(wv.z), th[i]);
            th[i] = pkfma(xp3, bc(wv.w), th[i]);
        }
    }
#pragma unroll
    for (int i = 0; i < 10; ++i) th[i] = wave_sum2(th[i], a32) + bc(pre_b[i]);

    // ---- layer 0 folded into the initial product state, then ring ----
    f2 re[16], im[16];
    fold0_pk(th, w_ry, sh_trig + 40, lane, re, im);
    cnot_ring_pk(re, im, cA, cB, lane);

    // ---- layers 1..3; layer 3 skips RZ (phase) and ring (permutation) ----
#pragma unroll 1
    for (int l = 1; l < 4; ++l) {
        float yc[10], ys[10];
#pragma unroll
        for (int q = 0; q < 10; ++q) {
            float2 v = sh_trig[l * 10 + q];
            yc[q] = v.x; ys[q] = v.y;
        }
        apply_ry2<9>(re, im, yc[0], ys[0], lane, a32, cv16, cv32);
        apply_ry2<8>(re, im, yc[1], ys[1], lane, a32, cv16, cv32);
        apply_ry2<7>(re, im, yc[2], ys[2], lane, a32, cv16, cv32);
        apply_ry2<6>(re, im, yc[3], ys[3], lane, a32, cv16, cv32);
        apply_ry2<5>(re, im, yc[4], ys[4], lane, a32, cv16, cv32);
        apply_ry2<4>(re, im, yc[5], ys[5], lane, a32, cv16, cv32);
        apply_ry2<3>(re, im, yc[6], ys[6], lane, a32, cv16, cv32);
        apply_ry2<2>(re, im, yc[7], ys[7], lane, a32, cv16, cv32);
        apply_ry2<1>(re, im, yc[8], ys[8], lane, a32, cv16, cv32);
        apply_ry2<0>(re, im, yc[9], ys[9], lane, a32, cv16, cv32);

        if (l < 3) {
            float zc[10], zs[10];
#pragma unroll
            for (int q = 0; q < 10; ++q) {
                float2 w = sh_trig[40 + l * 10 + q];
                zc[q] = w.x; zs[q] = w.y;
            }
            f2 p67r[4], p67i[4], p89r[4], p89i[4];
            build_rz_tables_pk(zc, zs, lane, p67r, p67i, p89r, p89i);
#pragma unroll
            for (int r = 0; r < 16; ++r) {
                const int j = r >> 2, k = r & 3;
                f2 t_r = pkfma(im[r], -p67i[j], re[r] * p67r[j]);
                f2 t_i = pkfma(im[r], p67r[j], re[r] * p67i[j]);
                re[r] = pkfma(t_i, -p89i[k], t_r * p89r[k]);
                im[r] = pkfma(t_i, p89r[k], t_r * p89i[k]);
            }
            cnot_ring_pk(re, im, cA, cB, lane);
        }
    }

    // ---- epilogue with the last CNOT ring folded into the coefficients.
    // Ring is GF(2)-linear: bit_j' = xor_{k<=j} bit_k (j>=1),
    // bit_0' = xor_{k=1..9} bit_k. So z'_j = prod_{k<=j} z_k,
    // z'_0 = z0*L5*R9 (z0^2=1). C'(t) = A_lane + L5*WR(r) +- t0.
    float A_lane = 0.f;
    float L = ((lane >> 5) & 1) ? -1.f : 1.f;  // z0 (qubit0 <-> lane bit5)
#pragma unroll
    for (int j = 1; j <= 5; ++j) {
        L = ((lane >> (5 - j)) & 1) ? -L : L;  // L = prefix product L_j
        A_lane += post_w[j] * L;
    }
    const float t0 = post_w[0] * (((lane >> 5) & 1) ? -L : L);  // w0*z0*L5
    const float Ap = A_lane + t0, Am = A_lane - t0;
    const float w6 = post_w[6], w7 = post_w[7], w8 = post_w[8], w9 = post_w[9];
    f2 acc = (f2){0.f, 0.f};
#pragma unroll
    for (int r = 0; r < 16; ++r) {
        // WR(r) = z6*(w6 + z7*(w7 + z8*(w8 + z9*w9))), signs compile-time
        float u = (r & 1) ? w8 - w9 : w8 + w9;       // w8 + z9*w9
        float v = (r & 2) ? w7 - u : w7 + u;         // w7 + z8*(...)
        float wv = (r & 4) ? w6 - v : w6 + v;        // w6 + z7*(...)
        float WR = (r & 8) ? -wv : wv;               // z6*(...)
        const float base = ((0x6996 >> r) & 1) ? Am : Ap;  // +- t0 via R9
        float coef = fmaf(L, WR, base);
        f2 p = pkfma(re[r], re[r], im[r] * im[r]);
        acc = pkfma(p, bc(coef), acc);
    }
    acc = wave_sum2(acc, a32);
    if (lane == 0) {
        out[b0] = acc.x + post_b[0];
        if (haveB) out[b1] = acc.y + post_b[0];
    }
}

extern "C" void kernel_launch(void* const* d_in, const int* in_sizes, int n_in,
                              void* d_out, int out_size, void* d_ws, size_t ws_size,
                              hipStream_t stream) {
    const float* x      = (const float*)d_in[0];
    const float* pre_w  = (const float*)d_in[1];
    const float* pre_b  = (const float*)d_in[2];
    const float* post_w = (const float*)d_in[3];
    const float* post_b = (const float*)d_in[4];
    const float* w_ry   = (const float*)d_in[5];
    const float* w_rz   = (const float*)d_in[6];
    float* out = (float*)d_out;
    (void)d_ws; (void)ws_size;

    const int B = in_sizes[0] / 512;  // 4096
    const int waves = (B + 1) / 2;    // 2 elements per wave
    dqc_main_kernel<<<(waves + 3) / 4, 256, 0, stream>>>(
        x, pre_w, pre_b, post_w, post_b, w_ry, w_rz, out, B);
}

// Round 8
// 94.833 us; speedup vs baseline: 1.0187x; 1.0038x over previous
//
#include <hip/hip_runtime.h>

#define DEV static __device__ __forceinline__

// ================= lane-exchange primitives =================
// DPP ctrl: 0xB1 quad_perm[1,0,3,2] (xor1) | 0x4E quad_perm[2,3,0,1] (xor2)
//           0x1B quad_perm[3,2,1,0] (xor3) | 0x128 row_ror:8 (xor8)
//           0x141 row_half_mirror (xor7)
template <int CTRL>
DEV float dpp_mov(float v) {
    int i = __float_as_int(v);
    i = __builtin_amdgcn_update_dpp(i, i, CTRL, 0xF, 0xF, false);
    return __int_as_float(i);
}
template <int PAT>
DEV float swz(float v) {
    return __int_as_float(__builtin_amdgcn_ds_swizzle(__float_as_int(v), PAT));
}
DEV float bperm(int byteaddr, float v) {
    return __int_as_float(__builtin_amdgcn_ds_bpermute(byteaddr, __float_as_int(v)));
}

#if __has_builtin(__builtin_amdgcn_permlane16_swap)
#define HAVE_PL16 1
DEV void pl16_pair(float v, float &r0, float &r1) {
    auto r = __builtin_amdgcn_permlane16_swap(__float_as_int(v), __float_as_int(v),
                                              false, false);
    r0 = __int_as_float((int)r[0]);
    r1 = __int_as_float((int)r[1]);
}
#endif
#if __has_builtin(__builtin_amdgcn_permlane32_swap)
#define HAVE_PL32 1
DEV void pl32_pair(float v, float &r0, float &r1) {
    auto r = __builtin_amdgcn_permlane32_swap(__float_as_int(v), __float_as_int(v),
                                              false, false);
    r0 = __int_as_float((int)r[0]);
    r1 = __int_as_float((int)r[1]);
}
#endif

// Full-wave sum; r0+r1 after a swap is own+partner regardless of direction.
DEV float wave_sum(float v, int a32) {
    v += dpp_mov<0xB1>(v);
    v += dpp_mov<0x4E>(v);
    v += dpp_mov<0x141>(v);
    v += dpp_mov<0x128>(v);
#ifdef HAVE_PL16
    {
        float r0, r1;
        pl16_pair(v, r0, r1);
        v = r0 + r1;
    }
#else
    v += swz<0x401F>(v);
#endif
#ifdef HAVE_PL32
    {
        float r0, r1;
        pl32_pair(v, r0, r1);
        v = r0 + r1;
    }
#else
    v += bperm(a32, v);
#endif
    return v;
}

// Qubit q <-> bit P = 9-q of state index s = lane*16 + r.
// Lane bits 5..0 = state bits 9..4; reg bits 3..0 = state bits 3..0.
template <int P>
DEV void apply_ry(float (&re)[16], float (&im)[16], float c, float s, int lane,
                  int a32, bool cv16, bool cv32) {
    if constexpr (P == 9) {
#ifdef HAVE_PL32
        const bool hi = (lane & 32) != 0;
        const float fl = hi ? s : c;
        const float fh = hi ? c : -s;
        const float g0 = cv32 ? fl : fh;
        const float g1 = cv32 ? fh : fl;
#pragma unroll
        for (int r = 0; r < 16; ++r) {
            float x0, x1, y0, y1;
            pl32_pair(re[r], x0, x1);
            pl32_pair(im[r], y0, y1);
            re[r] = fmaf(g0, x0, g1 * x1);
            im[r] = fmaf(g0, y0, g1 * y1);
        }
#else
        const float sg = (lane & 32) ? s : -s;
#pragma unroll
        for (int r = 0; r < 16; ++r) {
            float pr = bperm(a32, re[r]);
            float pi = bperm(a32, im[r]);
            re[r] = fmaf(c, re[r], sg * pr);
            im[r] = fmaf(c, im[r], sg * pi);
        }
#endif
    } else if constexpr (P == 8) {
#ifdef HAVE_PL16
        const bool hi = (lane & 16) != 0;
        const float fl = hi ? s : c;
        const float fh = hi ? c : -s;
        const float g0 = cv16 ? fl : fh;
        const float g1 = cv16 ? fh : fl;
#pragma unroll
        for (int r = 0; r < 16; ++r) {
            float x0, x1, y0, y1;
            pl16_pair(re[r], x0, x1);
            pl16_pair(im[r], y0, y1);
            re[r] = fmaf(g0, x0, g1 * x1);
            im[r] = fmaf(g0, y0, g1 * y1);
        }
#else
        const float sg = (lane & 16) ? s : -s;
#pragma unroll
        for (int r = 0; r < 16; ++r) {
            float pr = swz<0x401F>(re[r]);
            float pi = swz<0x401F>(im[r]);
            re[r] = fmaf(c, re[r], sg * pr);
            im[r] = fmaf(c, im[r], sg * pi);
        }
#endif
    } else if constexpr (P >= 4) {
        constexpr int mask = 1 << (P - 4);
        const float sg = (lane & mask) ? s : -s;
#pragma unroll
        for (int r = 0; r < 16; ++r) {
            float pr, pi;
            if constexpr (mask == 8) {
                pr = dpp_mov<0x128>(re[r]);
                pi = dpp_mov<0x128>(im[r]);
            } else if constexpr (mask == 4) {
                // xor4 = xor7 o xor3, both DPP (round-2 proven)
                pr = dpp_mov<0x1B>(dpp_mov<0x141>(re[r]));
                pi = dpp_mov<0x1B>(dpp_mov<0x141>(im[r]));
            } else if constexpr (mask == 2) {
                pr = dpp_mov<0x4E>(re[r]);
                pi = dpp_mov<0x4E>(im[r]);
            } else {
                pr = dpp_mov<0xB1>(re[r]);
                pi = dpp_mov<0xB1>(im[r]);
            }
            re[r] = fmaf(c, re[r], sg * pr);
            im[r] = fmaf(c, im[r], sg * pi);
        }
    } else {
        constexpr int tb = 1 << P;
#pragma unroll
        for (int r = 0; r < 16; ++r) {
            if (!(r & tb)) {
                const int r2 = r | tb;
                float a0r = re[r], a1r = re[r2];
                float a0i = im[r], a1i = im[r2];
                re[r]  = fmaf(c, a0r, -s * a1r);
                re[r2] = fmaf(s, a0r,  c * a1r);
                im[r]  = fmaf(c, a0i, -s * a1i);
                im[r2] = fmaf(s, a0i,  c * a1i);
            }
        }
    }
}

// Composed lane map of CNOT chain C(q0->q1)..C(q4->q5).
DEV int g_of(int a) {
    a ^= ((a >> 1) & 1) ? 1 : 0;
    a ^= ((a >> 2) & 1) ? 2 : 0;
    a ^= ((a >> 3) & 1) ? 4 : 0;
    a ^= ((a >> 4) & 1) ? 8 : 0;
    a ^= ((a >> 5) & 1) ? 16 : 0;
    return a;
}

// RZ phase tables for one layer (p67 has the q0..q5 lane phase folded in).
DEV void build_rz_tables(const float (&zc)[10], const float (&zs)[10], int lane,
                         float (&p67r)[4], float (&p67i)[4], float (&p89r)[4],
                         float (&p89i)[4]) {
    float plr, pli;
    pli = ((lane >> 5) & 1) ? zs[0] : -zs[0];
    plr = zc[0];
#pragma unroll
    for (int q = 1; q < 6; ++q) {
        float sq = ((lane >> (5 - q)) & 1) ? zs[q] : -zs[q];
        float nr = plr * zc[q] - pli * sq;
        float ni = plr * sq + pli * zc[q];
        plr = nr; pli = ni;
    }
    const float c6 = zc[6], s6 = zs[6], c7 = zc[7], s7 = zs[7];
    const float c8 = zc[8], s8 = zs[8], c9 = zc[9], s9 = zs[9];
#pragma unroll
    for (int j = 0; j < 4; ++j) {
        float sg6 = (j >> 1) ? s6 : -s6;  // qubit6 <-> reg bit 3
        float sg7 = (j & 1) ? s7 : -s7;   // qubit7 <-> reg bit 2
        float ar = c6 * c7 - sg6 * sg7;
        float ai = c6 * sg7 + sg6 * c7;
        p67r[j] = ar * plr - ai * pli;
        p67i[j] = ar * pli + ai * plr;
        float sg8 = (j >> 1) ? s8 : -s8;  // qubit8 <-> reg bit 1
        float sg9 = (j & 1) ? s9 : -s9;   // qubit9 <-> reg bit 0
        p89r[j] = c8 * c9 - sg8 * sg9;
        p89i[j] = c8 * sg9 + sg8 * c9;
    }
}

// CNOT ring (physical): composed lane perm + conditional reg swap + renames.
DEV void cnot_ring(float (&re)[16], float (&im)[16], int cA, int cB, int lane) {
#pragma unroll
    for (int r = 0; r < 16; ++r) {
        const int addr = ((0x6996 >> r) & 1) ? cB : cA;  // parity of r&15
        re[r] = bperm(addr, re[r]);
        im[r] = bperm(addr, im[r]);
    }
    {
        const bool ctrl = (lane & 1) != 0;  // C(q5->q6)
#pragma unroll
        for (int r = 0; r < 8; ++r) {
            const int r2 = r | 8;
            float t0 = re[r], t1 = re[r2];
            re[r]  = ctrl ? t1 : t0;
            re[r2] = ctrl ? t0 : t1;
            float u0 = im[r], u1 = im[r2];
            im[r]  = ctrl ? u1 : u0;
            im[r2] = ctrl ? u0 : u1;
        }
    }
    // register renames: C(q6->q7), C(q7->q8), C(q8->q9)
#pragma unroll
    for (int r = 0; r < 16; ++r)
        if ((r & 8) && !(r & 4)) {
            const int r2 = r | 4;
            float t = re[r]; re[r] = re[r2]; re[r2] = t;
            t = im[r]; im[r] = im[r2]; im[r2] = t;
        }
#pragma unroll
    for (int r = 0; r < 16; ++r)
        if ((r & 4) && !(r & 2)) {
            const int r2 = r | 2;
            float t = re[r]; re[r] = re[r2]; re[r2] = t;
            t = im[r]; im[r] = im[r2]; im[r2] = t;
        }
#pragma unroll
    for (int r = 0; r < 16; ++r)
        if ((r & 2) && !(r & 1)) {
            const int r2 = r | 1;
            float t = re[r]; re[r] = re[r2]; re[r2] = t;
            t = im[r]; im[r] = im[r2]; im[r2] = t;
        }
}

__global__ __launch_bounds__(256, 4) void dqc_main_kernel(
    const float* __restrict__ x, const float* __restrict__ pre_w,
    const float* __restrict__ pre_b, const float* __restrict__ post_w,
    const float* __restrict__ post_b, const float* __restrict__ w_ry,
    const float* __restrict__ w_rz, float* __restrict__ out, int B) {
    // Block-shared weight trig: [0..39] RY (row 0 unused), [40..79] RZ
    // (row 3 unused: last-layer RZ is a pure phase, cancels in |psi|^2).
    __shared__ float2 sh_trig[80];
    {
        int t = threadIdx.x;
        if (t < 80) {
            float ang = (t < 40 ? w_ry[t] : w_rz[t - 40]) * 0.5f;
            float sv, cv;
            __sincosf(ang, &sv, &cv);
            sh_trig[t] = make_float2(cv, sv);
        }
    }
    __syncthreads();

    const int lane = threadIdx.x & 63;
    const int wid = threadIdx.x >> 6;
    const int b = blockIdx.x * 4 + wid;   // one element per wave (4/SIMD TLP)
    if (b >= B) return;

    const int a32 = (lane ^ 32) << 2;

    // Probe permlane*_swap direction (wave-uniform).
    bool cv16 = false, cv32 = false;
#ifdef HAVE_PL16
    {
        auto r = __builtin_amdgcn_permlane16_swap(lane, lane, false, false);
        cv16 = ((int)r[0] == (lane & ~16));
    }
#endif
#ifdef HAVE_PL32
    {
        auto r = __builtin_amdgcn_permlane32_swap(lane, lane, false, false);
        cv32 = ((int)r[0] == (lane & ~32));
    }
#endif

    const int h0 = lane ^ ((lane & 1) ? 32 : 0);
    const int cA = g_of(h0) << 2;
    const int cB = g_of(h0 ^ 32) << 2;

    // ---- q_in[b, i] = x[b] . pre_w[i] + pre_b[i]  (float4 loads) ----
    float th[10];
#pragma unroll
    for (int i = 0; i < 10; ++i) th[i] = 0.f;
    const float4* xb4 = reinterpret_cast<const float4*>(x + (size_t)b * 512);
    const float4* pw4 = reinterpret_cast<const float4*>(pre_w);
#pragma unroll
    for (int k = 0; k < 2; ++k) {
        const int idx = lane + 64 * k;
        const float4 xv = xb4[idx];
#pragma unroll
        for (int i = 0; i < 10; ++i) {
            const float4 wv = pw4[i * 128 + idx];
            th[i] = fmaf(xv.x, wv.x, th[i]);
            th[i] = fmaf(xv.y, wv.y, th[i]);
            th[i] = fmaf(xv.z, wv.z, th[i]);
            th[i] = fmaf(xv.w, wv.w, th[i]);
        }
    }
#pragma unroll
    for (int i = 0; i < 10; ++i) th[i] = wave_sum(th[i], a32) + pre_b[i];

    // ================= layer 0 folded into the initial state ==============
    // Initial RY(th_q) and layer-0 RY(w_ry[0,q]) compose additively; the
    // pre-CNOT layer-0 state is a product state; apply the layer-0 RZ phases
    // per-qubit and build the complex product state directly.
    float f0r[10], f0i[10], f1r[10], f1i[10];
#pragma unroll
    for (int q = 0; q < 10; ++q) {
        float hh = 0.5f * (th[q] + w_ry[q]);  // w_ry row 0 (raw angle)
        float sh_, ch_;
        __sincosf(hh, &sh_, &ch_);
        float2 z = sh_trig[40 + q];           // (cos, sin) of w_rz[0,q]/2
        f0r[q] = ch_ * z.x;  f0i[q] = -ch_ * z.y;   // e^{-i z}
        f1r[q] = sh_ * z.x;  f1i[q] =  sh_ * z.y;   // e^{+i z}
    }
    float Lr, Li;
    {
        int bq = (lane >> 5) & 1;
        Lr = bq ? f1r[0] : f0r[0];
        Li = bq ? f1i[0] : f0i[0];
#pragma unroll
        for (int q = 1; q < 6; ++q) {
            int bb = (lane >> (5 - q)) & 1;
            float br = bb ? f1r[q] : f0r[q];
            float bi = bb ? f1i[q] : f0i[q];
            float nr = Lr * br - Li * bi;
            float ni = Lr * bi + Li * br;
            Lr = nr; Li = ni;
        }
    }
    float t67r[4], t67i[4], t89r[4], t89i[4];
#pragma unroll
    for (int j = 0; j < 4; ++j) {
        float ar = (j >> 1) ? f1r[6] : f0r[6];  // qubit6 <-> reg bit 3
        float ai = (j >> 1) ? f1i[6] : f0i[6];
        float br = (j & 1) ? f1r[7] : f0r[7];   // qubit7 <-> reg bit 2
        float bi = (j & 1) ? f1i[7] : f0i[7];
        float pr = ar * br - ai * bi;
        float pi = ar * bi + ai * br;
        t67r[j] = pr * Lr - pi * Li;            // lane factor folded in
        t67i[j] = pr * Li + pi * Lr;
        float cr_ = (j >> 1) ? f1r[8] : f0r[8]; // qubit8 <-> reg bit 1
        float ci_ = (j >> 1) ? f1i[8] : f0i[8];
        float dr = (j & 1) ? f1r[9] : f0r[9];   // qubit9 <-> reg bit 0
        float di = (j & 1) ? f1i[9] : f0i[9];
        t89r[j] = cr_ * dr - ci_ * di;
        t89i[j] = cr_ * di + ci_ * dr;
    }
    float re[16], im[16];
#pragma unroll
    for (int r = 0; r < 16; ++r) {
        const int j = r >> 2, k = r & 3;
        re[r] = t67r[j] * t89r[k] - t67i[j] * t89i[k];
        im[r] = t67r[j] * t89i[k] + t67i[j] * t89r[k];
    }
    cnot_ring(re, im, cA, cB, lane);

    // ---- layers 1..3; layer 3 skips RZ (phase) and ring (permutation) ----
#pragma unroll 1
    for (int l = 1; l < 4; ++l) {
        float yc[10], ys[10];
#pragma unroll
        for (int q = 0; q < 10; ++q) {
            float2 v = sh_trig[l * 10 + q];
            yc[q] = v.x; ys[q] = v.y;
        }
        apply_ry<9>(re, im, yc[0], ys[0], lane, a32, cv16, cv32);
        apply_ry<8>(re, im, yc[1], ys[1], lane, a32, cv16, cv32);
        apply_ry<7>(re, im, yc[2], ys[2], lane, a32, cv16, cv32);
        apply_ry<6>(re, im, yc[3], ys[3], lane, a32, cv16, cv32);
        apply_ry<5>(re, im, yc[4], ys[4], lane, a32, cv16, cv32);
        apply_ry<4>(re, im, yc[5], ys[5], lane, a32, cv16, cv32);
        apply_ry<3>(re, im, yc[6], ys[6], lane, a32, cv16, cv32);
        apply_ry<2>(re, im, yc[7], ys[7], lane, a32, cv16, cv32);
        apply_ry<1>(re, im, yc[8], ys[8], lane, a32, cv16, cv32);
        apply_ry<0>(re, im, yc[9], ys[9], lane, a32, cv16, cv32);

        if (l < 3) {
            float zc[10], zs[10];
#pragma unroll
            for (int q = 0; q < 10; ++q) {
                float2 w = sh_trig[40 + l * 10 + q];
                zc[q] = w.x; zs[q] = w.y;
            }
            float p67r[4], p67i[4], p89r[4], p89i[4];
            build_rz_tables(zc, zs, lane, p67r, p67i, p89r, p89i);
#pragma unroll
            for (int r = 0; r < 16; ++r) {
                const int j = r >> 2, k = r & 3;
                float t_r = re[r] * p67r[j] - im[r] * p67i[j];
                float t_i = re[r] * p67i[j] + im[r] * p67r[j];
                re[r] = t_r * p89r[k] - t_i * p89i[k];
                im[r] = t_r * p89i[k] + t_i * p89r[k];
            }
            cnot_ring(re, im, cA, cB, lane);
        }
    }

    // ---- epilogue with the last CNOT ring folded into the coefficients.
    // Ring is GF(2)-linear: bit_j' = xor_{k<=j} bit_k (j>=1),
    // bit_0' = xor_{k=1..9} bit_k. So z'_j = prod_{k<=j} z_k,
    // z'_0 = z0*L5*R9 (z0^2=1). C'(t) = A_lane + L5*WR(r) +- t0.
    float A_lane = 0.f;
    float L = ((lane >> 5) & 1) ? -1.f : 1.f;  // z0 (qubit0 <-> lane bit5)
#pragma unroll
    for (int j = 1; j <= 5; ++j) {
        L = ((lane >> (5 - j)) & 1) ? -L : L;  // L = prefix product L_j
        A_lane += post_w[j] * L;
    }
    const float t0 = post_w[0] * (((lane >> 5) & 1) ? -L : L);  // w0*z0*L5
    const float Ap = A_lane + t0, Am = A_lane - t0;
    const float w6 = post_w[6], w7 = post_w[7], w8 = post_w[8], w9 = post_w[9];
    float acc = 0.f;
#pragma unroll
    for (int r = 0; r < 16; ++r) {
        // WR(r) = z6*(w6 + z7*(w7 + z8*(w8 + z9*w9))), signs compile-time
        float u = (r & 1) ? w8 - w9 : w8 + w9;       // w8 + z9*w9
        float v = (r & 2) ? w7 - u : w7 + u;         // w7 + z8*(...)
        float wv = (r & 4) ? w6 - v : w6 + v;        // w6 + z7*(...)
        float WR = (r & 8) ? -wv : wv;               // z6*(...)
        const float base = ((0x6996 >> r) & 1) ? Am : Ap;  // +- t0 via R9
        float coef = fmaf(L, WR, base);
        float p = fmaf(re[r], re[r], im[r] * im[r]);
        acc = fmaf(p, coef, acc);
    }
    acc = wave_sum(acc, a32);
    if (lane == 0) out[b] = acc + post_b[0];
}

extern "C" void kernel_launch(void* const* d_in, const int* in_sizes, int n_in,
                              void* d_out, int out_size, void* d_ws, size_t ws_size,
                              hipStream_t stream) {
    const float* x      = (const float*)d_in[0];
    const float* pre_w  = (const float*)d_in[1];
    const float* pre_b  = (const float*)d_in[2];
    const float* post_w = (const float*)d_in[3];
    const float* post_b = (const float*)d_in[4];
    const float* w_ry   = (const float*)d_in[5];
    const float* w_rz   = (const float*)d_in[6];
    float* out = (float*)d_out;
    (void)d_ws; (void)ws_size;

    const int B = in_sizes[0] / 512;  // 4096, one element per wave
    dqc_main_kernel<<<(B + 3) / 4, 256, 0, stream>>>(x, pre_w, pre_b, post_w,
                                                     post_b, w_ry, w_rz, out, B);
}

// Round 9
// 94.329 us; speedup vs baseline: 1.0241x; 1.0053x over previous
//
#include <hip/hip_runtime.h>

#define DEV static __device__ __forceinline__

// ================= lane-exchange primitives =================
// DPP ctrl: 0xB1 quad_perm[1,0,3,2] (xor1) | 0x4E quad_perm[2,3,0,1] (xor2)
//           0x1B quad_perm[3,2,1,0] (xor3) | 0x128 row_ror:8 (xor8)
//           0x141 row_half_mirror (xor7)
template <int CTRL>
DEV float dpp_mov(float v) {
    int i = __float_as_int(v);
    i = __builtin_amdgcn_update_dpp(i, i, CTRL, 0xF, 0xF, false);
    return __int_as_float(i);
}
template <int PAT>
DEV float swz(float v) {
    return __int_as_float(__builtin_amdgcn_ds_swizzle(__float_as_int(v), PAT));
}
DEV float bperm(int byteaddr, float v) {
    return __int_as_float(__builtin_amdgcn_ds_bpermute(byteaddr, __float_as_int(v)));
}

#if __has_builtin(__builtin_amdgcn_permlane16_swap)
#define HAVE_PL16 1
DEV void pl16_pair(float v, float &r0, float &r1) {
    auto r = __builtin_amdgcn_permlane16_swap(__float_as_int(v), __float_as_int(v),
                                              false, false);
    r0 = __int_as_float((int)r[0]);
    r1 = __int_as_float((int)r[1]);
}
#endif
#if __has_builtin(__builtin_amdgcn_permlane32_swap)
#define HAVE_PL32 1
DEV void pl32_pair(float v, float &r0, float &r1) {
    auto r = __builtin_amdgcn_permlane32_swap(__float_as_int(v), __float_as_int(v),
                                              false, false);
    r0 = __int_as_float((int)r[0]);
    r1 = __int_as_float((int)r[1]);
}
#endif

// Full-wave sum; r0+r1 after a swap is own+partner regardless of direction.
DEV float wave_sum(float v, int a32) {
    v += dpp_mov<0xB1>(v);
    v += dpp_mov<0x4E>(v);
    v += dpp_mov<0x141>(v);
    v += dpp_mov<0x128>(v);
#ifdef HAVE_PL16
    {
        float r0, r1;
        pl16_pair(v, r0, r1);
        v = r0 + r1;
    }
#else
    v += swz<0x401F>(v);
#endif
#ifdef HAVE_PL32
    {
        float r0, r1;
        pl32_pair(v, r0, r1);
        v = r0 + r1;
    }
#else
    v += bperm(a32, v);
#endif
    return v;
}

// Qubit q <-> bit P = 9-q of state index s = lane*16 + r.
// Lane bits 5..0 = state bits 9..4; reg bits 3..0 = state bits 3..0.
template <int P>
DEV void apply_ry(float (&re)[16], float (&im)[16], float c, float s, int lane,
                  int a32, bool cv16, bool cv32) {
    if constexpr (P == 9) {
#ifdef HAVE_PL32
        const bool hi = (lane & 32) != 0;
        const float fl = hi ? s : c;
        const float fh = hi ? c : -s;
        const float g0 = cv32 ? fl : fh;
        const float g1 = cv32 ? fh : fl;
#pragma unroll
        for (int r = 0; r < 16; ++r) {
            float x0, x1, y0, y1;
            pl32_pair(re[r], x0, x1);
            pl32_pair(im[r], y0, y1);
            re[r] = fmaf(g0, x0, g1 * x1);
            im[r] = fmaf(g0, y0, g1 * y1);
        }
#else
        const float sg = (lane & 32) ? s : -s;
#pragma unroll
        for (int r = 0; r < 16; ++r) {
            float pr = bperm(a32, re[r]);
            float pi = bperm(a32, im[r]);
            re[r] = fmaf(c, re[r], sg * pr);
            im[r] = fmaf(c, im[r], sg * pi);
        }
#endif
    } else if constexpr (P == 8) {
#ifdef HAVE_PL16
        const bool hi = (lane & 16) != 0;
        const float fl = hi ? s : c;
        const float fh = hi ? c : -s;
        const float g0 = cv16 ? fl : fh;
        const float g1 = cv16 ? fh : fl;
#pragma unroll
        for (int r = 0; r < 16; ++r) {
            float x0, x1, y0, y1;
            pl16_pair(re[r], x0, x1);
            pl16_pair(im[r], y0, y1);
            re[r] = fmaf(g0, x0, g1 * x1);
            im[r] = fmaf(g0, y0, g1 * y1);
        }
#else
        const float sg = (lane & 16) ? s : -s;
#pragma unroll
        for (int r = 0; r < 16; ++r) {
            float pr = swz<0x401F>(re[r]);
            float pi = swz<0x401F>(im[r]);
            re[r] = fmaf(c, re[r], sg * pr);
            im[r] = fmaf(c, im[r], sg * pi);
        }
#endif
    } else if constexpr (P >= 4) {
        constexpr int mask = 1 << (P - 4);
        const float sg = (lane & mask) ? s : -s;
#pragma unroll
        for (int r = 0; r < 16; ++r) {
            float pr, pi;
            if constexpr (mask == 8) {
                pr = dpp_mov<0x128>(re[r]);
                pi = dpp_mov<0x128>(im[r]);
            } else if constexpr (mask == 4) {
                // xor4 = xor7 o xor3, both DPP (round-2 proven)
                pr = dpp_mov<0x1B>(dpp_mov<0x141>(re[r]));
                pi = dpp_mov<0x1B>(dpp_mov<0x141>(im[r]));
            } else if constexpr (mask == 2) {
                pr = dpp_mov<0x4E>(re[r]);
                pi = dpp_mov<0x4E>(im[r]);
            } else {
                pr = dpp_mov<0xB1>(re[r]);
                pi = dpp_mov<0xB1>(im[r]);
            }
            re[r] = fmaf(c, re[r], sg * pr);
            im[r] = fmaf(c, im[r], sg * pi);
        }
    } else {
        constexpr int tb = 1 << P;
#pragma unroll
        for (int r = 0; r < 16; ++r) {
            if (!(r & tb)) {
                const int r2 = r | tb;
                float a0r = re[r], a1r = re[r2];
                float a0i = im[r], a1i = im[r2];
                re[r]  = fmaf(c, a0r, -s * a1r);
                re[r2] = fmaf(s, a0r,  c * a1r);
                im[r]  = fmaf(c, a0i, -s * a1i);
                im[r2] = fmaf(s, a0i,  c * a1i);
            }
        }
    }
}

// Composed lane map of CNOT chain C(q0->q1)..C(q4->q5).
DEV int g_of(int a) {
    a ^= ((a >> 1) & 1) ? 1 : 0;
    a ^= ((a >> 2) & 1) ? 2 : 0;
    a ^= ((a >> 3) & 1) ? 4 : 0;
    a ^= ((a >> 4) & 1) ? 8 : 0;
    a ^= ((a >> 5) & 1) ? 16 : 0;
    return a;
}

// RZ phase tables for one layer (p67 has the q0..q5 lane phase folded in).
DEV void build_rz_tables(const float (&zc)[10], const float (&zs)[10], int lane,
                         float (&p67r)[4], float (&p67i)[4], float (&p89r)[4],
                         float (&p89i)[4]) {
    float plr, pli;
    pli = ((lane >> 5) & 1) ? zs[0] : -zs[0];
    plr = zc[0];
#pragma unroll
    for (int q = 1; q < 6; ++q) {
        float sq = ((lane >> (5 - q)) & 1) ? zs[q] : -zs[q];
        float nr = plr * zc[q] - pli * sq;
        float ni = plr * sq + pli * zc[q];
        plr = nr; pli = ni;
    }
    const float c6 = zc[6], s6 = zs[6], c7 = zc[7], s7 = zs[7];
    const float c8 = zc[8], s8 = zs[8], c9 = zc[9], s9 = zs[9];
#pragma unroll
    for (int j = 0; j < 4; ++j) {
        float sg6 = (j >> 1) ? s6 : -s6;  // qubit6 <-> reg bit 3
        float sg7 = (j & 1) ? s7 : -s7;   // qubit7 <-> reg bit 2
        float ar = c6 * c7 - sg6 * sg7;
        float ai = c6 * sg7 + sg6 * c7;
        p67r[j] = ar * plr - ai * pli;
        p67i[j] = ar * pli + ai * plr;
        float sg8 = (j >> 1) ? s8 : -s8;  // qubit8 <-> reg bit 1
        float sg9 = (j & 1) ? s9 : -s9;   // qubit9 <-> reg bit 0
        p89r[j] = c8 * c9 - sg8 * sg9;
        p89i[j] = c8 * sg9 + sg8 * c9;
    }
}

// CNOT ring (physical): composed lane perm + conditional reg swap + renames.
DEV void cnot_ring(float (&re)[16], float (&im)[16], int cA, int cB, int lane) {
#pragma unroll
    for (int r = 0; r < 16; ++r) {
        const int addr = ((0x6996 >> r) & 1) ? cB : cA;  // parity of r&15
        re[r] = bperm(addr, re[r]);
        im[r] = bperm(addr, im[r]);
    }
    {
        const bool ctrl = (lane & 1) != 0;  // C(q5->q6)
#pragma unroll
        for (int r = 0; r < 8; ++r) {
            const int r2 = r | 8;
            float t0 = re[r], t1 = re[r2];
            re[r]  = ctrl ? t1 : t0;
            re[r2] = ctrl ? t0 : t1;
            float u0 = im[r], u1 = im[r2];
            im[r]  = ctrl ? u1 : u0;
            im[r2] = ctrl ? u0 : u1;
        }
    }
    // register renames: C(q6->q7), C(q7->q8), C(q8->q9)
#pragma unroll
    for (int r = 0; r < 16; ++r)
        if ((r & 8) && !(r & 4)) {
            const int r2 = r | 4;
            float t = re[r]; re[r] = re[r2]; re[r2] = t;
            t = im[r]; im[r] = im[r2]; im[r2] = t;
        }
#pragma unroll
    for (int r = 0; r < 16; ++r)
        if ((r & 4) && !(r & 2)) {
            const int r2 = r | 2;
            float t = re[r]; re[r] = re[r2]; re[r2] = t;
            t = im[r]; im[r] = im[r2]; im[r2] = t;
        }
#pragma unroll
    for (int r = 0; r < 16; ++r)
        if ((r & 2) && !(r & 1)) {
            const int r2 = r | 1;
            float t = re[r]; re[r] = re[r2]; re[r2] = t;
            t = im[r]; im[r] = im[r2]; im[r2] = t;
        }
}

__global__ __launch_bounds__(256, 4) void dqc_main_kernel(
    const float* __restrict__ x, const float* __restrict__ pre_w,
    const float* __restrict__ pre_b, const float* __restrict__ post_w,
    const float* __restrict__ post_b, const float* __restrict__ w_ry,
    const float* __restrict__ w_rz, float* __restrict__ out, int B) {
    // Block-shared weight trig: [0..39] RY (row 0 unused), [40..79] RZ
    // (rows 2,3 of RZ... row 3 unused: last-layer RZ cancels in |psi|^2).
    __shared__ float2 sh_trig[80];
    {
        int t = threadIdx.x;
        if (t < 80) {
            float ang = (t < 40 ? w_ry[t] : w_rz[t - 40]) * 0.5f;
            float sv, cv;
            __sincosf(ang, &sv, &cv);
            sh_trig[t] = make_float2(cv, sv);
        }
    }
    __syncthreads();

    const int lane = threadIdx.x & 63;
    const int wid = threadIdx.x >> 6;
    const int b = blockIdx.x * 4 + wid;   // one element per wave (4/SIMD TLP)
    if (b >= B) return;

    const int a32 = (lane ^ 32) << 2;

    // Probe permlane*_swap direction (wave-uniform).
    bool cv16 = false, cv32 = false;
#ifdef HAVE_PL16
    {
        auto r = __builtin_amdgcn_permlane16_swap(lane, lane, false, false);
        cv16 = ((int)r[0] == (lane & ~16));
    }
#endif
#ifdef HAVE_PL32
    {
        auto r = __builtin_amdgcn_permlane32_swap(lane, lane, false, false);
        cv32 = ((int)r[0] == (lane & ~32));
    }
#endif

    const int h0 = lane ^ ((lane & 1) ? 32 : 0);
    const int cA = g_of(h0) << 2;
    const int cB = g_of(h0 ^ 32) << 2;

    // ---- q_in[b, i] = x[b] . pre_w[i] + pre_b[i]  (float4 loads) ----
    float th[10];
#pragma unroll
    for (int i = 0; i < 10; ++i) th[i] = 0.f;
    const float4* xb4 = reinterpret_cast<const float4*>(x + (size_t)b * 512);
    const float4* pw4 = reinterpret_cast<const float4*>(pre_w);
#pragma unroll
    for (int k = 0; k < 2; ++k) {
        const int idx = lane + 64 * k;
        const float4 xv = xb4[idx];
#pragma unroll
        for (int i = 0; i < 10; ++i) {
            const float4 wv = pw4[i * 128 + idx];
            th[i] = fmaf(xv.x, wv.x, th[i]);
            th[i] = fmaf(xv.y, wv.y, th[i]);
            th[i] = fmaf(xv.z, wv.z, th[i]);
            th[i] = fmaf(xv.w, wv.w, th[i]);
        }
    }
#pragma unroll
    for (int i = 0; i < 10; ++i) th[i] = wave_sum(th[i], a32) + pre_b[i];

    // ================= layer 0 folded into the initial state ==============
    float f0r[10], f0i[10], f1r[10], f1i[10];
#pragma unroll
    for (int q = 0; q < 10; ++q) {
        float hh = 0.5f * (th[q] + w_ry[q]);  // w_ry row 0 (raw angle)
        float sh_, ch_;
        __sincosf(hh, &sh_, &ch_);
        float2 z = sh_trig[40 + q];           // (cos, sin) of w_rz[0,q]/2
        f0r[q] = ch_ * z.x;  f0i[q] = -ch_ * z.y;   // e^{-i z}
        f1r[q] = sh_ * z.x;  f1i[q] =  sh_ * z.y;   // e^{+i z}
    }
    float Lr, Li;
    {
        int bq = (lane >> 5) & 1;
        Lr = bq ? f1r[0] : f0r[0];
        Li = bq ? f1i[0] : f0i[0];
#pragma unroll
        for (int q = 1; q < 6; ++q) {
            int bb = (lane >> (5 - q)) & 1;
            float br = bb ? f1r[q] : f0r[q];
            float bi = bb ? f1i[q] : f0i[q];
            float nr = Lr * br - Li * bi;
            float ni = Lr * bi + Li * br;
            Lr = nr; Li = ni;
        }
    }
    float t67r[4], t67i[4], t89r[4], t89i[4];
#pragma unroll
    for (int j = 0; j < 4; ++j) {
        float ar = (j >> 1) ? f1r[6] : f0r[6];  // qubit6 <-> reg bit 3
        float ai = (j >> 1) ? f1i[6] : f0i[6];
        float br = (j & 1) ? f1r[7] : f0r[7];   // qubit7 <-> reg bit 2
        float bi = (j & 1) ? f1i[7] : f0i[7];
        float pr = ar * br - ai * bi;
        float pi = ar * bi + ai * br;
        t67r[j] = pr * Lr - pi * Li;            // lane factor folded in
        t67i[j] = pr * Li + pi * Lr;
        float cr_ = (j >> 1) ? f1r[8] : f0r[8]; // qubit8 <-> reg bit 1
        float ci_ = (j >> 1) ? f1i[8] : f0i[8];
        float dr = (j & 1) ? f1r[9] : f0r[9];   // qubit9 <-> reg bit 0
        float di = (j & 1) ? f1i[9] : f0i[9];
        t89r[j] = cr_ * dr - ci_ * di;
        t89i[j] = cr_ * di + ci_ * dr;
    }
    float re[16], im[16];
#pragma unroll
    for (int r = 0; r < 16; ++r) {
        const int j = r >> 2, k = r & 3;
        re[r] = t67r[j] * t89r[k] - t67i[j] * t89i[k];
        im[r] = t67r[j] * t89i[k] + t67i[j] * t89r[k];
    }
    cnot_ring(re, im, cA, cB, lane);

    // ---- layers 1..2; ring after layer 1 only (ring 2 is frame-skipped) --
#pragma unroll 1
    for (int l = 1; l < 3; ++l) {
        float yc[10], ys[10];
#pragma unroll
        for (int q = 0; q < 10; ++q) {
            float2 v = sh_trig[l * 10 + q];
            yc[q] = v.x; ys[q] = v.y;
        }
        apply_ry<9>(re, im, yc[0], ys[0], lane, a32, cv16, cv32);
        apply_ry<8>(re, im, yc[1], ys[1], lane, a32, cv16, cv32);
        apply_ry<7>(re, im, yc[2], ys[2], lane, a32, cv16, cv32);
        apply_ry<6>(re, im, yc[3], ys[3], lane, a32, cv16, cv32);
        apply_ry<5>(re, im, yc[4], ys[4], lane, a32, cv16, cv32);
        apply_ry<4>(re, im, yc[5], ys[5], lane, a32, cv16, cv32);
        apply_ry<3>(re, im, yc[6], ys[6], lane, a32, cv16, cv32);
        apply_ry<2>(re, im, yc[7], ys[7], lane, a32, cv16, cv32);
        apply_ry<1>(re, im, yc[8], ys[8], lane, a32, cv16, cv32);
        apply_ry<0>(re, im, yc[9], ys[9], lane, a32, cv16, cv32);

        float zc[10], zs[10];
#pragma unroll
        for (int q = 0; q < 10; ++q) {
            float2 w = sh_trig[40 + l * 10 + q];
            zc[q] = w.x; zs[q] = w.y;
        }
        float p67r[4], p67i[4], p89r[4], p89i[4];
        build_rz_tables(zc, zs, lane, p67r, p67i, p89r, p89i);
#pragma unroll
        for (int r = 0; r < 16; ++r) {
            const int j = r >> 2, k = r & 3;
            float t_r = re[r] * p67r[j] - im[r] * p67i[j];
            float t_i = re[r] * p67i[j] + im[r] * p67r[j];
            re[r] = t_r * p89r[k] - t_i * p89i[k];
            im[r] = t_r * p89i[k] + t_i * p89r[k];
        }
        if (l == 1) cnot_ring(re, im, cA, cB, lane);
    }

    // ======== layer 3 RYs in the ring-2-skipped frame ====================
    // Stored s <-> physical t = R s (R = the CNOT ring, GF(2)-linear).
    // Gate on qubit q: pair mask R^{-1}e_q, sign sigma(s) = <row_q(R), s>.
    // R^{-1}e_q = {q,q+1} (q<=8), {0,1,9} (q=9); row_q(R) = prefix sets.
    {
        float yc[10], ys[10];
#pragma unroll
        for (int q = 0; q < 10; ++q) {
            float2 v = sh_trig[30 + q];
            yc[q] = v.x; ys[q] = v.y;
        }
        const int a48 = (lane ^ 48) << 2;
        const int p1F = __popc(lane & 0x1F) & 1;
        const int p30 = __popc(lane & 0x30) & 1;
        const int p38 = __popc(lane & 0x38) & 1;
        const int p3C = __popc(lane & 0x3C) & 1;
        const int p3E = __popc(lane & 0x3E) & 1;
        const int p3F = __popc(lane & 0x3F) & 1;

        // q=0: m = lane^0x30; sigma = p1F ^ parity(r)
        {
            const float c = yc[0], s = ys[0];
            const float sg0 = p1F ? s : -s;
#pragma unroll
            for (int r = 0; r < 16; ++r) {
                const float sg = ((0x6996 >> r) & 1) ? -sg0 : sg0;
                float pr = bperm(a48, re[r]);
                float pi = bperm(a48, im[r]);
                re[r] = fmaf(c, re[r], sg * pr);
                im[r] = fmaf(c, im[r], sg * pi);
            }
        }
        // q=1: m = lane^24 (swz); sigma = p30
        {
            const float c = yc[1], s = ys[1];
            const float sg = p30 ? s : -s;
#pragma unroll
            for (int r = 0; r < 16; ++r) {
                float pr = swz<0x601F>(re[r]);
                float pi = swz<0x601F>(im[r]);
                re[r] = fmaf(c, re[r], sg * pr);
                im[r] = fmaf(c, im[r], sg * pi);
            }
        }
        // q=2: m = lane^12; sigma = p38
        {
            const float c = yc[2], s = ys[2];
            const float sg = p38 ? s : -s;
#pragma unroll
            for (int r = 0; r < 16; ++r) {
                float pr = swz<0x301F>(re[r]);
                float pi = swz<0x301F>(im[r]);
                re[r] = fmaf(c, re[r], sg * pr);
                im[r] = fmaf(c, im[r], sg * pi);
            }
        }
        // q=3: m = lane^6; sigma = p3C
        {
            const float c = yc[3], s = ys[3];
            const float sg = p3C ? s : -s;
#pragma unroll
            for (int r = 0; r < 16; ++r) {
                float pr = swz<0x181F>(re[r]);
                float pi = swz<0x181F>(im[r]);
                re[r] = fmaf(c, re[r], sg * pr);
                im[r] = fmaf(c, im[r], sg * pi);
            }
        }
        // q=4: m = lane^3 (dpp 0x1B); sigma = p3E
        {
            const float c = yc[4], s = ys[4];
            const float sg = p3E ? s : -s;
#pragma unroll
            for (int r = 0; r < 16; ++r) {
                float pr = dpp_mov<0x1B>(re[r]);
                float pi = dpp_mov<0x1B>(im[r]);
                re[r] = fmaf(c, re[r], sg * pr);
                im[r] = fmaf(c, im[r], sg * pi);
            }
        }
        // q=5: m = lane^1 + reg^8; sigma = p3F (uniform in r)
        {
            const float c = yc[5], s = ys[5];
            const float sg = p3F ? s : -s;
#pragma unroll
            for (int r = 0; r < 8; ++r) {
                const int r2 = r | 8;
                float prL = dpp_mov<0xB1>(re[r2]);
                float prH = dpp_mov<0xB1>(re[r]);
                float piL = dpp_mov<0xB1>(im[r2]);
                float piH = dpp_mov<0xB1>(im[r]);
                re[r]  = fmaf(c, re[r],  sg * prL);
                re[r2] = fmaf(c, re[r2], sg * prH);
                im[r]  = fmaf(c, im[r],  sg * piL);
                im[r2] = fmaf(c, im[r2], sg * piH);
            }
        }
        // q=6: m = reg^12; sigma = p3F ^ bit3(r)
        {
            const float c = yc[6], s = ys[6];
            const float sg0 = p3F ? s : -s;   // bit3=0 side
#pragma unroll
            for (int r = 0; r < 8; ++r) {
                const int r2 = r ^ 12;
                float a0r = re[r], a1r = re[r2];
                float a0i = im[r], a1i = im[r2];
                re[r]  = fmaf(c, a0r,  sg0 * a1r);
                re[r2] = fmaf(c, a1r, -sg0 * a0r);
                im[r]  = fmaf(c, a0i,  sg0 * a1i);
                im[r2] = fmaf(c, a1i, -sg0 * a0i);
            }
        }
        // q=7: m = reg^6; sigma = p3F ^ parity(r & 0xC)
        {
            const float c = yc[7], s = ys[7];
            const float sg0 = p3F ? s : -s;
#pragma unroll
            for (int r = 0; r < 16; ++r) {
                if (!(r & 4)) {   // bit2=0 side of the pair
                    const int r2 = r ^ 6;
                    const float sgA = (r & 8) ? -sg0 : sg0;  // par(r&0xC)=bit3
                    float a0r = re[r], a1r = re[r2];
                    float a0i = im[r], a1i = im[r2];
                    re[r]  = fmaf(c, a0r,  sgA * a1r);
                    re[r2] = fmaf(c, a1r, -sgA * a0r);
                    im[r]  = fmaf(c, a0i,  sgA * a1i);
                    im[r2] = fmaf(c, a1i, -sgA * a0i);
                }
            }
        }
        // q=8: m = reg^3; sigma = p3F ^ parity(r & 0xE)
        {
            const float c = yc[8], s = ys[8];
            const float sg0 = p3F ? s : -s;
#pragma unroll
            for (int r = 0; r < 16; ++r) {
                if (!(r & 2)) {   // bit1=0 side
                    const int r2 = r ^ 3;
                    // par(r&0xE) with bit1=0 -> parity(bit3,bit2)
                    const float sgA =
                        ((__builtin_popcount(r & 0xC) & 1)) ? -sg0 : sg0;
                    float a0r = re[r], a1r = re[r2];
                    float a0i = im[r], a1i = im[r2];
                    re[r]  = fmaf(c, a0r,  sgA * a1r);
                    re[r2] = fmaf(c, a1r, -sgA * a0r);
                    im[r]  = fmaf(c, a0i,  sgA * a1i);
                    im[r2] = fmaf(c, a1i, -sgA * a0i);
                }
            }
        }
        // q=9: m = lane^48 + reg^1; sigma = p3F ^ parity(r)
        {
            const float c = yc[9], s = ys[9];
            const float sg0 = p3F ? s : -s;
#pragma unroll
            for (int r = 0; r < 16; ++r) {
                if (!(r & 1)) {   // bit0=0 side
                    const int r2 = r | 1;
                    const float sgA = ((0x6996 >> r) & 1) ? -sg0 : sg0;
                    float prL = bperm(a48, re[r2]);
                    float prH = bperm(a48, re[r]);
                    float piL = bperm(a48, im[r2]);
                    float piH = bperm(a48, im[r]);
                    re[r]  = fmaf(c, re[r],   sgA * prL);
                    re[r2] = fmaf(c, re[r2], -sgA * prH);
                    im[r]  = fmaf(c, im[r],   sgA * piL);
                    im[r2] = fmaf(c, im[r2], -sgA * piH);
                }
            }
        }
    }

    // ---- epilogue folding BOTH pending rings: C(R^2 s) ----
    // zeta_j(s) = (-1)^{<row_j(R^2), s>}; rows split lane/reg:
    // j: Lmask,Rmask = 0:(35,5) 1:(2F,F) 2:(17,F) 3:(2B,F) 4:(15,F)
    //                  5:(2A,F) 6:(15,7) 7:(2A,B) 8:(15,5) 9:(2A,A)
    {
        const float sg35 = (__popc(lane & 0x35) & 1) ? -1.f : 1.f;
        const float sg2F = (__popc(lane & 0x2F) & 1) ? -1.f : 1.f;
        const float sg17 = (__popc(lane & 0x17) & 1) ? -1.f : 1.f;
        const float sg2B = (__popc(lane & 0x2B) & 1) ? -1.f : 1.f;
        const float sg15 = (__popc(lane & 0x15) & 1) ? -1.f : 1.f;
        const float sg2A = (__popc(lane & 0x2A) & 1) ? -1.f : 1.f;
        const float G5 = post_w[0] * sg35 + post_w[8] * sg15;  // reg 0x5
        const float GF = post_w[1] * sg2F + post_w[2] * sg17 +
                         post_w[3] * sg2B + post_w[4] * sg15 +
                         post_w[5] * sg2A;                     // reg 0xF
        const float G7 = post_w[6] * sg15;                     // reg 0x7
        const float GB = post_w[7] * sg2A;                     // reg 0xB
        const float GA = post_w[9] * sg2A;                     // reg 0xA
        float acc = 0.f;
#pragma unroll
        for (int r = 0; r < 16; ++r) {
            float coef = ((__builtin_popcount(r & 0x5) & 1) ? -G5 : G5) +
                         ((__builtin_popcount(r & 0xF) & 1) ? -GF : GF) +
                         ((__builtin_popcount(r & 0x7) & 1) ? -G7 : G7) +
                         ((__builtin_popcount(r & 0xB) & 1) ? -GB : GB) +
                         ((__builtin_popcount(r & 0xA) & 1) ? -GA : GA);
            float p = fmaf(re[r], re[r], im[r] * im[r]);
            acc = fmaf(p, coef, acc);
        }
        acc = wave_sum(acc, a32);
        if (lane == 0) out[b] = acc + post_b[0];
    }
}

extern "C" void kernel_launch(void* const* d_in, const int* in_sizes, int n_in,
                              void* d_out, int out_size, void* d_ws, size_t ws_size,
                              hipStream_t stream) {
    const float* x      = (const float*)d_in[0];
    const float* pre_w  = (const float*)d_in[1];
    const float* pre_b  = (const float*)d_in[2];
    const float* post_w = (const float*)d_in[3];
    const float* post_b = (const float*)d_in[4];
    const float* w_ry   = (const float*)d_in[5];
    const float* w_rz   = (const float*)d_in[6];
    float* out = (float*)d_out;
    (void)d_ws; (void)ws_size;

    const int B = in_sizes[0] / 512;  // 4096, one element per wave
    dqc_main_kernel<<<(B + 3) / 4, 256, 0, stream>>>(x, pre_w, pre_b, post_w,
                                                     post_b, w_ry, w_rz, out, B);
}